// Round 3
// baseline (668.158 us; speedup 1.0000x reference)
//
#include <hip/hip_runtime.h>
#include <hip/hip_bf16.h>

#define N_REL 8

typedef unsigned short ushort_t;
typedef unsigned int uint_t;
typedef __attribute__((ext_vector_type(8))) short short8;   // bf16x8 MFMA operand
typedef __attribute__((ext_vector_type(4))) float floatx4;  // MFMA accumulator

static __device__ __forceinline__ ushort_t f2bf(float f) {
    union { float f; unsigned u; } v; v.f = f;
    unsigned r = v.u + 0x7fff + ((v.u >> 16) & 1);
    return (ushort_t)(r >> 16);
}

typedef __attribute__((address_space(1))) void glob_void;
typedef __attribute__((address_space(3))) void lds_void;

static __device__ __forceinline__ void load_lds16(const void* g, void* l) {
    __builtin_amdgcn_global_load_lds((glob_void*)g, (lds_void*)l, 16, 0, 0);
}

// Stage one 128x64 bf16 half-tile (16 KB) from global [rows][K] into LDS, linear
// [r][chunk] layout, with the st-swizzle (chunk ^= r&7) pre-applied on the GLOBAL
// source address (global_load_lds writes wave-uniform-base + lane*16 only).
static __device__ __forceinline__ void stage_half(const ushort_t* __restrict__ g,
                                                  int row0, int rmax, int K, int k0,
                                                  ushort_t* lds, int w, int l) {
    const int rl = l >> 3;
    const int gc = ((l & 7) ^ rl) * 8;  // swizzled 16B chunk within the row
#pragma unroll
    for (int s = 0; s < 2; ++s) {
        int r = row0 + s * 64 + w * 8 + rl;
        r = r < rmax ? r : rmax - 1;  // clamp (stores are guarded; dup rows harmless)
        load_lds16(g + (size_t)r * K + k0 + gc, lds + (s * 64 + w * 8) * 64);
    }
}

// ---------------- sort infrastructure ----------------

__global__ __launch_bounds__(256) void hist_kernel(const int* __restrict__ dst,
                                                   const int* __restrict__ et,
                                                   int* __restrict__ cnt, int E) {
    int e = blockIdx.x * blockDim.x + threadIdx.x;
    if (e < E) atomicAdd(&cnt[dst[e] * N_REL + et[e]], 1);
}

__global__ __launch_bounds__(256) void scan1(const int* __restrict__ cnt,
                                             int* __restrict__ off,
                                             int* __restrict__ bsum, int nk) {
    __shared__ int s[256];
    int t = threadIdx.x;
    int k = blockIdx.x * 256 + t;
    int v = k < nk ? cnt[k] : 0;
    s[t] = v; __syncthreads();
    for (int d = 1; d < 256; d <<= 1) {
        int x = (t >= d) ? s[t - d] : 0;
        __syncthreads(); s[t] += x; __syncthreads();
    }
    if (k < nk) off[k] = s[t] - v;
    if (t == 255) bsum[blockIdx.x] = s[255];
}

__global__ __launch_bounds__(1024) void scan2(int* __restrict__ bsum, int nb) {
    __shared__ int s[1024];
    int t = threadIdx.x;
    int v = t < nb ? bsum[t] : 0;
    s[t] = v; __syncthreads();
    for (int d = 1; d < 1024; d <<= 1) {
        int x = (t >= d) ? s[t - d] : 0;
        __syncthreads(); s[t] += x; __syncthreads();
    }
    if (t < nb) bsum[t] = s[t] - v;
}

__global__ __launch_bounds__(256) void scan3(int* __restrict__ off,
                                             const int* __restrict__ bsum,
                                             int* __restrict__ cursor,
                                             int nk) {
    int k = blockIdx.x * 256 + threadIdx.x;
    if (k >= nk) return;
    int o = off[k] + bsum[k >> 8];
    off[k] = o;
    cursor[k] = o;
}

// stores src[e] directly (not e) — removes one dependent load in the gather loop
__global__ __launch_bounds__(256) void scatter_src(const int* __restrict__ dst,
                                                   const int* __restrict__ et,
                                                   const int* __restrict__ src,
                                                   int* __restrict__ cursor,
                                                   int* __restrict__ esrc, int E) {
    int e = blockIdx.x * blockDim.x + threadIdx.x;
    if (e < E) {
        int key = dst[e] * N_REL + et[e];
        int pos = atomicAdd(&cursor[key], 1);
        esrc[pos] = src[e];
    }
}

// ---------------- casts ----------------

__global__ __launch_bounds__(256) void cast_bf16(const float* __restrict__ in,
                                                 ushort_t* __restrict__ out, long n) {
    long idx = ((long)blockIdx.x * blockDim.x + threadIdx.x) * 4;
    if (idx + 4 <= n) {
        float4 v = *(const float4*)(in + idx);
        ushort_t o[4] = {f2bf(v.x), f2bf(v.y), f2bf(v.z), f2bf(v.w)};
        *(uint2*)(out + idx) = *(const uint2*)o;
    } else {
        for (; idx < n; ++idx) out[idx] = f2bf(in[idx]);
    }
}

// in: [z][K][N] fp32 -> out: [z][N][K] bf16.
__global__ __launch_bounds__(256) void transpose_cast(const float* __restrict__ in,
                                                      ushort_t* __restrict__ out,
                                                      int K, int N) {
    __shared__ float tile[32][33];
    const float* inp = in + (size_t)blockIdx.z * K * N;
    ushort_t* outp = out + (size_t)blockIdx.z * K * N;
    int n0 = blockIdx.x * 32, k0 = blockIdx.y * 32;
    int tx = threadIdx.x & 31, ty = threadIdx.x >> 5;
#pragma unroll
    for (int s = 0; s < 4; ++s)
        tile[ty + 8 * s][tx] = inp[(size_t)(k0 + ty + 8 * s) * N + n0 + tx];
    __syncthreads();
#pragma unroll
    for (int s = 0; s < 4; ++s)
        outp[(size_t)(n0 + ty + 8 * s) * K + k0 + tx] = f2bf(tile[tx][ty + 8 * s]);
}

// ---------------- persistent 256x256 8-phase MFMA GEMM: C = A @ Bt^T ------------
// Verified 8-phase core (T2 st-swizzle + T3/T4 counted vmcnt + T5 setprio),
// now PERSISTENT: grid = 256 blocks, each loops over tiles T, T+256, ...
// The end-of-tile stage guard slots (ph2/3/4 of window nkt-2 and ph1..4 of
// window nkt-1) map 1:1 onto the prologue's 7 half-tile stages of the NEXT
// tile (same buffer slots, k wraps to 0/1, rows bm2/bn2) — so the pipeline
// never drains across tiles. Epilogue uses a separate 16 KB LDS buffer with
// raw s_barrier + manual lgkmcnt (never __syncthreads → no vmcnt(0) drain).
// vmcnt retires IN ORDER, so epilogue stores mixed into the count only make
// the vmcnt(6) waits more conservative, never less.

#define STAGE_A(b, h, ktx)                                                              \
    do {                                                                                \
        int kx_ = (ktx);                                                                \
        if (kx_ < nkt)                                                                  \
            stage_half(A, bm + (h) * 128, M, K, kx_ << 6, &sh.st[(b)][0][(h)][0], w, l);\
        else if (have_next)                                                             \
            stage_half(A, bm2 + (h) * 128, M, K, (kx_ - nkt) << 6,                      \
                       &sh.st[(b)][0][(h)][0], w, l);                                   \
    } while (0)

#define STAGE_B(b, h, ktx)                                                              \
    do {                                                                                \
        int kx_ = (ktx);                                                                \
        if (kx_ < nkt)                                                                  \
            stage_half(Bt, bn + (h) * 128, N, K, kx_ << 6, &sh.st[(b)][1][(h)][0], w, l);\
        else if (have_next)                                                             \
            stage_half(Bt, bn2 + (h) * 128, N, K, (kx_ - nkt) << 6,                     \
                       &sh.st[(b)][1][(h)][0], w, l);                                   \
    } while (0)

#define LOAD_A(b, qm)                                                          \
    {                                                                          \
        const ushort_t* pa_ = &sh.st[(b)][0][(qm)][0];                         \
        _Pragma("unroll") for (int i_ = 0; i_ < 4; ++i_) {                     \
            const int r_ = wm * 64 + i_ * 16 + l16;                            \
            _Pragma("unroll") for (int kk_ = 0; kk_ < 2; ++kk_) {              \
                const int ch_ = (kk_ * 4 + quad) ^ (r_ & 7);                   \
                areg[i_][kk_] = *(const short8*)&pa_[r_ * 64 + ch_ * 8];       \
            }                                                                  \
        }                                                                      \
    }

#define LOAD_B(b, qn)                                                          \
    {                                                                          \
        const ushort_t* pb_ = &sh.st[(b)][1][(qn)][0];                         \
        _Pragma("unroll") for (int j_ = 0; j_ < 2; ++j_) {                     \
            const int r_ = wn * 32 + j_ * 16 + l16;                            \
            _Pragma("unroll") for (int kk_ = 0; kk_ < 2; ++kk_) {              \
                const int ch_ = (kk_ * 4 + quad) ^ (r_ & 7);                   \
                breg[(qn)][j_][kk_] = *(const short8*)&pb_[r_ * 64 + ch_ * 8]; \
            }                                                                  \
        }                                                                      \
    }

#define MFMA_Q(qm, qn)                                                              \
    _Pragma("unroll") for (int i_ = 0; i_ < 4; ++i_)                                \
        _Pragma("unroll") for (int j_ = 0; j_ < 2; ++j_)                            \
            _Pragma("unroll") for (int kk_ = 0; kk_ < 2; ++kk_)                     \
                acc[(qm)][(qn)][i_][j_] = __builtin_amdgcn_mfma_f32_16x16x32_bf16(  \
                    areg[i_][kk_], breg[(qn)][j_][kk_], acc[(qm)][(qn)][i_][j_], 0, 0, 0);

#define PHASE_SYNC()                                                           \
    __builtin_amdgcn_s_barrier();                                              \
    asm volatile("s_waitcnt lgkmcnt(0)" ::: "memory");                         \
    __builtin_amdgcn_sched_barrier(0)

#define WINDOW(kt, b)                                                          \
    {                                                                          \
        /* phase 1: quadrant (0,0) — reads Ah0, Bh0 */                         \
        LOAD_A(b, 0);                                                          \
        LOAD_B(b, 0);                                                          \
        STAGE_A((b) ^ 1, 1, (kt) + 1);                                         \
        PHASE_SYNC();                                                          \
        __builtin_amdgcn_s_setprio(1);                                         \
        MFMA_Q(0, 0);                                                          \
        __builtin_amdgcn_s_setprio(0);                                         \
        __builtin_amdgcn_s_barrier();                                          \
        /* phase 2: quadrant (0,1) — reads Bh1; Ah0 now free */                \
        LOAD_B(b, 1);                                                          \
        STAGE_A(b, 0, (kt) + 2);                                               \
        PHASE_SYNC();                                                          \
        __builtin_amdgcn_s_setprio(1);                                         \
        MFMA_Q(0, 1);                                                          \
        __builtin_amdgcn_s_setprio(0);                                         \
        __builtin_amdgcn_s_barrier();                                          \
        /* phase 3: quadrant (1,0) — reads Ah1; Bh0 free */                    \
        LOAD_A(b, 1);                                                          \
        STAGE_B(b, 0, (kt) + 2);                                               \
        PHASE_SYNC();                                                          \
        __builtin_amdgcn_s_setprio(1);                                         \
        MFMA_Q(1, 0);                                                          \
        __builtin_amdgcn_s_setprio(0);                                         \
        __builtin_amdgcn_s_barrier();                                          \
        /* phase 4: quadrant (1,1) — no ds_reads; Bh1 free; counted vmcnt */   \
        STAGE_B(b, 1, (kt) + 2);                                               \
        if ((kt) + 2 < nkt || have_next) {                                     \
            asm volatile("s_waitcnt vmcnt(6)" ::: "memory");                   \
        } else {                                                               \
            asm volatile("s_waitcnt vmcnt(0)" ::: "memory"); /* final drain */ \
        }                                                                      \
        __builtin_amdgcn_s_barrier();                                          \
        __builtin_amdgcn_sched_barrier(0);                                     \
        __builtin_amdgcn_s_setprio(1);                                         \
        MFMA_Q(1, 1);                                                          \
        __builtin_amdgcn_s_setprio(0);                                         \
        __builtin_amdgcn_s_barrier();                                          \
    }

__global__ __launch_bounds__(512, 2) void gemm256p(const ushort_t* __restrict__ A,
                                                   const ushort_t* __restrict__ Bt,
                                                   ushort_t* __restrict__ C,
                                                   int M, int K, int N,
                                                   int ntiles, int nx) {
    __shared__ struct {
        __align__(16) ushort_t st[2][2][2][128 * 64];  // [buf][A/B][half] 128 KB
        __align__(16) ushort_t c2[32 * 256];           // epilogue staging 16 KB
    } sh;

    const int t = threadIdx.x;
    const int l = t & 63;
    const int w = t >> 6;
    const int wm = w >> 2, wn = w & 3;
    const int quad = l >> 4, l16 = l & 15;

    const int nkt = K >> 6;
    const int q8 = ntiles >> 3, r8 = ntiles & 7;

    // bijective XCD-aware swizzle (m204) applied to the flat tile index
    int T = blockIdx.x;
    if (T >= ntiles) return;
    int bm, bn, bm2 = 0, bn2 = 0;
    {
        const int xcd = T & 7;
        const int wgid = ((xcd < r8) ? xcd * (q8 + 1) : r8 * (q8 + 1) + (xcd - r8) * q8) + (T >> 3);
        bm = (wgid / nx) * 256;
        bn = (wgid % nx) * 256;
    }
    int Tn = T + gridDim.x;
    bool have_next = Tn < ntiles;
    if (have_next) {
        const int xcd = Tn & 7;
        const int wgid = ((xcd < r8) ? xcd * (q8 + 1) : r8 * (q8 + 1) + (xcd - r8) * q8) + (Tn >> 3);
        bm2 = (wgid / nx) * 256;
        bn2 = (wgid % nx) * 256;
    }

    floatx4 acc[2][2][4][2];
    short8 areg[4][2];
    short8 breg[2][2][2];

    // prologue: tile0 fully, tile1 all but Ah1; vmcnt(6) retires exactly tile0
    STAGE_A(0, 0, 0); STAGE_B(0, 0, 0); STAGE_B(0, 1, 0); STAGE_A(0, 1, 0);
    STAGE_A(1, 0, 1); STAGE_B(1, 0, 1); STAGE_B(1, 1, 1);
    asm volatile("s_waitcnt vmcnt(6)" ::: "memory");
    __builtin_amdgcn_s_barrier();

    while (true) {
#pragma unroll
        for (int a = 0; a < 2; ++a)
#pragma unroll
            for (int bq = 0; bq < 2; ++bq)
#pragma unroll
                for (int i = 0; i < 4; ++i)
#pragma unroll
                    for (int j = 0; j < 2; ++j) acc[a][bq][i][j] = (floatx4)(0.f);

        for (int kt = 0; kt < nkt; kt += 2) {
            WINDOW(kt, 0);
            WINDOW(kt + 1, 1);
        }

        // ---- epilogue: 8 passes of 32 rows via c2; raw barriers only ----
#pragma unroll
        for (int pc = 0; pc < 8; ++pc) {
            const int qm = pc >> 2;
            const int wmSel = (pc >> 1) & 1;
            const int ih = pc & 1;
            if (wm == wmSel) {
#pragma unroll
                for (int qn = 0; qn < 2; ++qn)
#pragma unroll
                    for (int io = 0; io < 2; ++io)
#pragma unroll
                        for (int j = 0; j < 2; ++j) {
                            const int cl = qn * 128 + wn * 32 + j * 16 + l16;
                            const int i = ih * 2 + io;
#pragma unroll
                            for (int rg = 0; rg < 4; ++rg)
                                sh.c2[(io * 16 + quad * 4 + rg) * 256 + cl] =
                                    f2bf(acc[qm][qn][i][j][rg]);
                        }
            }
            asm volatile("s_waitcnt lgkmcnt(0)" ::: "memory");
            __builtin_amdgcn_s_barrier();
#pragma unroll
            for (int it = 0; it < 2; ++it) {
                const int idx = it * 512 + t;
                const int rl = idx >> 5;
                const int ch8 = (idx & 31) * 8;
                const int grow = bm + pc * 32 + rl;
                if (grow < M)
                    *(uint4*)(C + (size_t)grow * N + bn + ch8) =
                        *(const uint4*)&sh.c2[rl * 256 + ch8];
            }
            __builtin_amdgcn_s_barrier();
        }

        if (!have_next) break;
        T = Tn; bm = bm2; bn = bn2;
        Tn += gridDim.x;
        have_next = Tn < ntiles;
        if (have_next) {
            const int xcd = Tn & 7;
            const int wgid = ((xcd < r8) ? xcd * (q8 + 1) : r8 * (q8 + 1) + (xcd - r8) * q8) + (Tn >> 3);
            bm2 = (wgid / nx) * 256;
            bn2 = (wgid % nx) * 256;
        }
    }
}

#undef STAGE_A
#undef STAGE_B
#undef LOAD_A
#undef LOAD_B
#undef MFMA_Q
#undef PHASE_SYNC
#undef WINDOW

// ---------------- fully-fused segmented mean + root + bias (+relu/cast) ----------
// Flat edge list per dst (segments for (d,0..7) are CONTIGUOUS in esrc). LDS
// tables give per-edge {1/c, relation column offset}; gathers issued in batches
// of 8 independent loads for MLP. One block per dst; 2 dims per thread.

template <int DIM, bool L1MODE>
__global__ __launch_bounds__(DIM / 2) void segsum_flat(const ushort_t* __restrict__ H,
                                                       const float* __restrict__ bias,
                                                       const int* __restrict__ off,
                                                       const int* __restrict__ cnt,
                                                       const int* __restrict__ esrc,
                                                       ushort_t* __restrict__ outb,
                                                       float* __restrict__ outf) {
    const int d = blockIdx.x;
    const int t = threadIdx.x;
    const int hs = (N_REL + 1) * DIM;
    __shared__ float s_inv[256];
    __shared__ int s_ro[256];

    const int base = off[d * N_REL];
    const int total = off[d * N_REL + N_REL - 1] + cnt[d * N_REL + N_REL - 1] - base;

    const ushort_t* __restrict__ Hcol = H + 2 * t;
    uint_t ur = *(const uint_t*)(Hcol + (size_t)d * hs);  // root part
    float2 bv = *(const float2*)(bias + 2 * t);
    float a0 = __uint_as_float(ur << 16) + bv.x;
    float a1 = __uint_as_float(ur & 0xffff0000u) + bv.y;

    for (int ch = 0; ch < total; ch += 256) {
        const int hi = min(total, ch + 256);
        if (t < N_REL) {
            int key = d * N_REL + t;
            int c = cnt[key];
            int o = off[key] - base;
            float inv = 1.0f / (float)(c > 0 ? c : 1);
            int ro = (t + 1) * DIM;
            for (int k = 0; k < c; ++k) {
                int pos = o + k;
                if (pos >= ch && pos < hi) { s_inv[pos & 255] = inv; s_ro[pos & 255] = ro; }
            }
        }
        __syncthreads();
        int p = ch;
        while (p + 8 <= hi) {
            int ss[8], ro[8];
            float iv[8];
            uint_t uu[8];
#pragma unroll
            for (int q = 0; q < 8; ++q) ss[q] = esrc[base + p + q];
#pragma unroll
            for (int q = 0; q < 8; ++q) { iv[q] = s_inv[(p + q) & 255]; ro[q] = s_ro[(p + q) & 255]; }
#pragma unroll
            for (int q = 0; q < 8; ++q) uu[q] = *(const uint_t*)(Hcol + (size_t)ss[q] * hs + ro[q]);
#pragma unroll
            for (int q = 0; q < 8; ++q) {
                a0 += iv[q] * __uint_as_float(uu[q] << 16);
                a1 += iv[q] * __uint_as_float(uu[q] & 0xffff0000u);
            }
            p += 8;
        }
        if (p + 4 <= hi) {
            int ss[4], ro[4];
            float iv[4];
            uint_t uu[4];
#pragma unroll
            for (int q = 0; q < 4; ++q) ss[q] = esrc[base + p + q];
#pragma unroll
            for (int q = 0; q < 4; ++q) { iv[q] = s_inv[(p + q) & 255]; ro[q] = s_ro[(p + q) & 255]; }
#pragma unroll
            for (int q = 0; q < 4; ++q) uu[q] = *(const uint_t*)(Hcol + (size_t)ss[q] * hs + ro[q]);
#pragma unroll
            for (int q = 0; q < 4; ++q) {
                a0 += iv[q] * __uint_as_float(uu[q] << 16);
                a1 += iv[q] * __uint_as_float(uu[q] & 0xffff0000u);
            }
            p += 4;
        }
        for (; p < hi; ++p) {
            int s = esrc[base + p];
            float iv = s_inv[p & 255];
            int ro = s_ro[p & 255];
            uint_t u = *(const uint_t*)(Hcol + (size_t)s * hs + ro);
            a0 += iv * __uint_as_float(u << 16);
            a1 += iv * __uint_as_float(u & 0xffff0000u);
        }
        __syncthreads();
    }

    if (L1MODE) {
        a0 = fmaxf(a0, 0.f);
        a1 = fmaxf(a1, 0.f);
        ushort_t o2[2] = {f2bf(a0), f2bf(a1)};
        *(uint_t*)(outb + (size_t)d * DIM + 2 * t) = *(const uint_t*)o2;
    } else {
        *(float2*)(outf + (size_t)d * DIM + 2 * t) = make_float2(a0, a1);
    }
}

// ---------------- launcher ----------------

extern "C" void kernel_launch(void* const* d_in, const int* in_sizes, int n_in,
                              void* d_out, int out_size, void* d_ws, size_t ws_size,
                              hipStream_t stream) {
    const float* x     = (const float*)d_in[0];
    const int*   eidx  = (const int*)d_in[1];
    const int*   etype = (const int*)d_in[2];
    const float* W1    = (const float*)d_in[3];
    const float* root1 = (const float*)d_in[4];
    const float* b1    = (const float*)d_in[5];
    const float* W2    = (const float*)d_in[6];
    const float* root2 = (const float*)d_in[7];
    const float* b2    = (const float*)d_in[8];
    float* out = (float*)d_out;

    const int IN_DIM = 1280, HID_DIM = 512, OUT_DIM = 256;
    const int E = in_sizes[2];
    const int N = in_sizes[0] / IN_DIM;
    const int NK = N * N_REL;
    const int* srcs = eidx;
    const int* dsts = eidx + E;

    char* ws = (char*)d_ws;
    size_t offb = 0;
    auto alloc = [&](size_t bytes) { void* p = ws + offb; offb += (bytes + 255) & ~(size_t)255; return p; };
    int*      cnt    = (int*)alloc((size_t)NK * 4);
    int*      off    = (int*)alloc((size_t)NK * 4);
    int*      cursor = (int*)alloc((size_t)NK * 4);
    int*      bsum   = (int*)alloc(1024 * 4);
    int*      esrc   = (int*)alloc((size_t)E * 4);
    ushort_t* x_bf   = (ushort_t*)alloc((size_t)N * IN_DIM * 2);   // reused as hb_bf later
    ushort_t* rW1t   = (ushort_t*)alloc((size_t)(N_REL + 1) * IN_DIM * HID_DIM * 2);
    ushort_t* r1t    = rW1t;
    ushort_t* W1t    = rW1t + (size_t)HID_DIM * IN_DIM;
    ushort_t* rW2t   = (ushort_t*)alloc((size_t)(N_REL + 1) * HID_DIM * OUT_DIM * 2);
    ushort_t* r2t    = rW2t;
    ushort_t* W2t    = rW2t + (size_t)OUT_DIM * HID_DIM;
    ushort_t* Hb     = (ushort_t*)alloc((size_t)N * (N_REL + 1) * HID_DIM * 2);  // 184 MB
    ushort_t* hb_bf  = x_bf;  // x_bf dead after layer-1 GEMM
    (void)ws_size;

    const int nb = (NK + 255) / 256;

    // 1) sort edges by (dst, rel); store src directly
    hipMemsetAsync(cnt, 0, (size_t)NK * 4, stream);
    hist_kernel<<<(E + 255) / 256, 256, 0, stream>>>(dsts, etype, cnt, E);
    scan1<<<nb, 256, 0, stream>>>(cnt, off, bsum, NK);
    scan2<<<1, 1024, 0, stream>>>(bsum, nb);
    scan3<<<nb, 256, 0, stream>>>(off, bsum, cursor, NK);
    scatter_src<<<(E + 255) / 256, 256, 0, stream>>>(dsts, etype, srcs, cursor, esrc, E);

    // 2) casts / weight transposes (into the concatenated Bt buffers)
    {
        long n = (long)N * IN_DIM;
        cast_bf16<<<(unsigned)((n / 4 + 255) / 256), 256, 0, stream>>>(x, x_bf, n);
    }
    transpose_cast<<<dim3(HID_DIM / 32, IN_DIM / 32, 1), 256, 0, stream>>>(root1, r1t, IN_DIM, HID_DIM);
    transpose_cast<<<dim3(HID_DIM / 32, IN_DIM / 32, N_REL), 256, 0, stream>>>(W1, W1t, IN_DIM, HID_DIM);
    transpose_cast<<<dim3(OUT_DIM / 32, HID_DIM / 32, 1), 256, 0, stream>>>(root2, r2t, HID_DIM, OUT_DIM);
    transpose_cast<<<dim3(OUT_DIM / 32, HID_DIM / 32, N_REL), 256, 0, stream>>>(W2, W2t, HID_DIM, OUT_DIM);

    const int mb = (N + 255) / 256;  // 79

    // 3) layer 1: persistent fused GEMM (root + 8 relations) -> segsum+relu+cast
    {
        const int NTOT = (N_REL + 1) * HID_DIM;  // 4608
        const int nxg = NTOT / 256;              // 18
        const int ntiles = mb * nxg;             // 1422
        gemm256p<<<256, 512, 0, stream>>>(x_bf, rW1t, Hb, N, IN_DIM, NTOT, ntiles, nxg);
        segsum_flat<512, true><<<N, 256, 0, stream>>>(Hb, b1, off, cnt, esrc, hb_bf, nullptr);
    }

    // 4) layer 2: persistent fused GEMM -> segsum -> out
    {
        const int NTOT = (N_REL + 1) * OUT_DIM;  // 2304
        const int nxg = NTOT / 256;              // 9
        const int ntiles = mb * nxg;             // 711
        gemm256p<<<256, 512, 0, stream>>>(hb_bf, rW2t, Hb, N, HID_DIM, NTOT, ntiles, nxg);
        segsum_flat<256, false><<<N, 128, 0, stream>>>(Hb, b2, off, cnt, esrc, nullptr, out);
    }
}

// Round 4
// 612.706 us; speedup vs baseline: 1.0905x; 1.0905x over previous
//
#include <hip/hip_runtime.h>
#include <hip/hip_bf16.h>

#define N_REL 8

typedef unsigned short ushort_t;
typedef unsigned int uint_t;
typedef __attribute__((ext_vector_type(8))) short short8;   // bf16x8 MFMA operand
typedef __attribute__((ext_vector_type(4))) float floatx4;  // MFMA accumulator

static __device__ __forceinline__ ushort_t f2bf(float f) {
    union { float f; unsigned u; } v; v.f = f;
    unsigned r = v.u + 0x7fff + ((v.u >> 16) & 1);
    return (ushort_t)(r >> 16);
}

typedef __attribute__((address_space(1))) void glob_void;
typedef __attribute__((address_space(3))) void lds_void;

static __device__ __forceinline__ void load_lds16(const void* g, void* l) {
    __builtin_amdgcn_global_load_lds((glob_void*)g, (lds_void*)l, 16, 0, 0);
}

// Stage one 128x64 bf16 half-tile (16 KB) from global [rows][K] into LDS, linear
// [r][chunk] layout, with the st-swizzle (chunk ^= r&7) pre-applied on the GLOBAL
// source address (global_load_lds writes wave-uniform-base + lane*16 only).
static __device__ __forceinline__ void stage_half(const ushort_t* __restrict__ g,
                                                  int row0, int rmax, int K, int k0,
                                                  ushort_t* lds, int w, int l) {
    const int rl = l >> 3;
    const int gc = ((l & 7) ^ rl) * 8;  // swizzled 16B chunk within the row
#pragma unroll
    for (int s = 0; s < 2; ++s) {
        int r = row0 + s * 64 + w * 8 + rl;
        r = r < rmax ? r : rmax - 1;  // clamp (stores are guarded; dup rows harmless)
        load_lds16(g + (size_t)r * K + k0 + gc, lds + (s * 64 + w * 8) * 64);
    }
}

// ---------------- sort infrastructure ----------------

__global__ __launch_bounds__(256) void hist_kernel(const int* __restrict__ dst,
                                                   const int* __restrict__ et,
                                                   int* __restrict__ cnt, int E) {
    int e = blockIdx.x * blockDim.x + threadIdx.x;
    if (e < E) atomicAdd(&cnt[dst[e] * N_REL + et[e]], 1);
}

__global__ __launch_bounds__(256) void scan1(const int* __restrict__ cnt,
                                             int* __restrict__ off,
                                             int* __restrict__ bsum, int nk) {
    __shared__ int s[256];
    int t = threadIdx.x;
    int k = blockIdx.x * 256 + t;
    int v = k < nk ? cnt[k] : 0;
    s[t] = v; __syncthreads();
    for (int d = 1; d < 256; d <<= 1) {
        int x = (t >= d) ? s[t - d] : 0;
        __syncthreads(); s[t] += x; __syncthreads();
    }
    if (k < nk) off[k] = s[t] - v;
    if (t == 255) bsum[blockIdx.x] = s[255];
}

__global__ __launch_bounds__(1024) void scan2(int* __restrict__ bsum, int nb) {
    __shared__ int s[1024];
    int t = threadIdx.x;
    int v = t < nb ? bsum[t] : 0;
    s[t] = v; __syncthreads();
    for (int d = 1; d < 1024; d <<= 1) {
        int x = (t >= d) ? s[t - d] : 0;
        __syncthreads(); s[t] += x; __syncthreads();
    }
    if (t < nb) bsum[t] = s[t] - v;
}

__global__ __launch_bounds__(256) void scan3(int* __restrict__ off,
                                             const int* __restrict__ bsum,
                                             int* __restrict__ cursor,
                                             int nk) {
    int k = blockIdx.x * 256 + threadIdx.x;
    if (k >= nk) return;
    int o = off[k] + bsum[k >> 8];
    off[k] = o;
    cursor[k] = o;
}

// Packs everything the gather loop needs into one 8-byte descriptor per edge:
// {src | rel<<27, 1.0f/count}. cnt[] is final (hist completed) when this runs.
__global__ __launch_bounds__(256) void scatter_desc(const int* __restrict__ dst,
                                                    const int* __restrict__ et,
                                                    const int* __restrict__ src,
                                                    const int* __restrict__ cnt,
                                                    int* __restrict__ cursor,
                                                    uint2* __restrict__ edesc, int E) {
    int e = blockIdx.x * blockDim.x + threadIdx.x;
    if (e < E) {
        int key = dst[e] * N_REL + et[e];
        int pos = atomicAdd(&cursor[key], 1);
        float inv = 1.0f / (float)cnt[key];
        edesc[pos] = make_uint2((uint_t)src[e] | ((uint_t)et[e] << 27),
                                __float_as_uint(inv));
    }
}

// ---------------- casts ----------------

__global__ __launch_bounds__(256) void cast_bf16(const float* __restrict__ in,
                                                 ushort_t* __restrict__ out, long n) {
    long idx = ((long)blockIdx.x * blockDim.x + threadIdx.x) * 4;
    if (idx + 4 <= n) {
        float4 v = *(const float4*)(in + idx);
        ushort_t o[4] = {f2bf(v.x), f2bf(v.y), f2bf(v.z), f2bf(v.w)};
        *(uint2*)(out + idx) = *(const uint2*)o;
    } else {
        for (; idx < n; ++idx) out[idx] = f2bf(in[idx]);
    }
}

// in: [z][K][N] fp32 -> out: [z][N][K] bf16.
__global__ __launch_bounds__(256) void transpose_cast(const float* __restrict__ in,
                                                      ushort_t* __restrict__ out,
                                                      int K, int N) {
    __shared__ float tile[32][33];
    const float* inp = in + (size_t)blockIdx.z * K * N;
    ushort_t* outp = out + (size_t)blockIdx.z * K * N;
    int n0 = blockIdx.x * 32, k0 = blockIdx.y * 32;
    int tx = threadIdx.x & 31, ty = threadIdx.x >> 5;
#pragma unroll
    for (int s = 0; s < 4; ++s)
        tile[ty + 8 * s][tx] = inp[(size_t)(k0 + ty + 8 * s) * N + n0 + tx];
    __syncthreads();
#pragma unroll
    for (int s = 0; s < 4; ++s)
        outp[(size_t)(n0 + ty + 8 * s) * K + k0 + tx] = f2bf(tile[tx][ty + 8 * s]);
}

// ---------------- 256x256 8-phase MFMA GEMM: C[M,N] = A[M,K] @ Bt[N,K]^T ---------
// Verified 8-phase template (T2 st-swizzle + T3/T4 counted vmcnt + T5 setprio).
// 512 threads = 8 waves (2M x 4N), BK=64, LDS = 128 KiB double-buffered.
// (Round-3 persistent variant regressed 268->307us — reverted to this version.)

#define STAGE_A(b, h, ktx) stage_half(A, bm + (h) * 128, M, K, ((ktx) << 6), &sh.st[(b)][0][(h)][0], w, l)
#define STAGE_B(b, h, ktx) stage_half(Bt, bn + (h) * 128, N, K, ((ktx) << 6), &sh.st[(b)][1][(h)][0], w, l)

#define LOAD_A(b, qm)                                                          \
    {                                                                          \
        const ushort_t* pa_ = &sh.st[(b)][0][(qm)][0];                         \
        _Pragma("unroll") for (int i_ = 0; i_ < 4; ++i_) {                     \
            const int r_ = wm * 64 + i_ * 16 + l16;                            \
            _Pragma("unroll") for (int kk_ = 0; kk_ < 2; ++kk_) {              \
                const int ch_ = (kk_ * 4 + quad) ^ (r_ & 7);                   \
                areg[i_][kk_] = *(const short8*)&pa_[r_ * 64 + ch_ * 8];       \
            }                                                                  \
        }                                                                      \
    }

#define LOAD_B(b, qn)                                                          \
    {                                                                          \
        const ushort_t* pb_ = &sh.st[(b)][1][(qn)][0];                         \
        _Pragma("unroll") for (int j_ = 0; j_ < 2; ++j_) {                     \
            const int r_ = wn * 32 + j_ * 16 + l16;                            \
            _Pragma("unroll") for (int kk_ = 0; kk_ < 2; ++kk_) {              \
                const int ch_ = (kk_ * 4 + quad) ^ (r_ & 7);                   \
                breg[(qn)][j_][kk_] = *(const short8*)&pb_[r_ * 64 + ch_ * 8]; \
            }                                                                  \
        }                                                                      \
    }

#define MFMA_Q(qm, qn)                                                              \
    _Pragma("unroll") for (int i_ = 0; i_ < 4; ++i_)                                \
        _Pragma("unroll") for (int j_ = 0; j_ < 2; ++j_)                            \
            _Pragma("unroll") for (int kk_ = 0; kk_ < 2; ++kk_)                     \
                acc[(qm)][(qn)][i_][j_] = __builtin_amdgcn_mfma_f32_16x16x32_bf16(  \
                    areg[i_][kk_], breg[(qn)][j_][kk_], acc[(qm)][(qn)][i_][j_], 0, 0, 0);

#define PHASE_SYNC()                                                           \
    __builtin_amdgcn_s_barrier();                                              \
    asm volatile("s_waitcnt lgkmcnt(0)" ::: "memory");                         \
    __builtin_amdgcn_sched_barrier(0)

#define WINDOW(kt, b)                                                          \
    {                                                                          \
        /* phase 1: quadrant (0,0) — reads Ah0, Bh0 */                         \
        LOAD_A(b, 0);                                                          \
        LOAD_B(b, 0);                                                          \
        if ((kt) + 1 < nkt) STAGE_A((b) ^ 1, 1, (kt) + 1);                     \
        PHASE_SYNC();                                                          \
        __builtin_amdgcn_s_setprio(1);                                         \
        MFMA_Q(0, 0);                                                          \
        __builtin_amdgcn_s_setprio(0);                                         \
        __builtin_amdgcn_s_barrier();                                          \
        /* phase 2: quadrant (0,1) — reads Bh1; Ah0 now free */                \
        LOAD_B(b, 1);                                                          \
        if ((kt) + 2 < nkt) STAGE_A(b, 0, (kt) + 2);                           \
        PHASE_SYNC();                                                          \
        __builtin_amdgcn_s_setprio(1);                                         \
        MFMA_Q(0, 1);                                                          \
        __builtin_amdgcn_s_setprio(0);                                         \
        __builtin_amdgcn_s_barrier();                                          \
        /* phase 3: quadrant (1,0) — reads Ah1; Bh0 free */                    \
        LOAD_A(b, 1);                                                          \
        if ((kt) + 2 < nkt) STAGE_B(b, 0, (kt) + 2);                           \
        PHASE_SYNC();                                                          \
        __builtin_amdgcn_s_setprio(1);                                         \
        MFMA_Q(1, 0);                                                          \
        __builtin_amdgcn_s_setprio(0);                                         \
        __builtin_amdgcn_s_barrier();                                          \
        /* phase 4: quadrant (1,1) — no ds_reads; Bh1 free; counted vmcnt */   \
        if ((kt) + 2 < nkt) {                                                  \
            STAGE_B(b, 1, (kt) + 2);                                           \
            asm volatile("s_waitcnt vmcnt(6)" ::: "memory");                   \
        } else {                                                               \
            asm volatile("s_waitcnt vmcnt(0)" ::: "memory"); /* epilogue drain */ \
        }                                                                      \
        __builtin_amdgcn_s_barrier();                                          \
        __builtin_amdgcn_sched_barrier(0);                                     \
        __builtin_amdgcn_s_setprio(1);                                         \
        MFMA_Q(1, 1);                                                          \
        __builtin_amdgcn_s_setprio(0);                                         \
        __builtin_amdgcn_s_barrier();                                          \
    }

__global__ __launch_bounds__(512, 2) void gemm256(const ushort_t* __restrict__ A,
                                                  const ushort_t* __restrict__ Bt,
                                                  ushort_t* __restrict__ C,
                                                  int M, int K, int N) {
    __shared__ union {
        __align__(16) ushort_t st[2][2][2][128 * 64];  // [buf][A/B][half][r*64+c]
        __align__(16) ushort_t c[256 * 256];           // bf16 epilogue staging (128 KB)
    } sh;

    const int t = threadIdx.x;
    const int l = t & 63;
    const int w = t >> 6;
    const int wm = w >> 2, wn = w & 3;
    const int quad = l >> 4, l16 = l & 15;

    // bijective XCD-aware swizzle (m204): consecutive wgids land on one XCD
    const int nx = gridDim.x;
    const int nwg = nx * gridDim.y;
    const int orig = blockIdx.y * nx + blockIdx.x;
    const int q8 = nwg >> 3, r8 = nwg & 7;
    const int xcd = orig & 7;
    const int wgid = ((xcd < r8) ? xcd * (q8 + 1) : r8 * (q8 + 1) + (xcd - r8) * q8) + (orig >> 3);
    const int bm = (wgid / nx) * 256;
    const int bn = (wgid % nx) * 256;

    const int nkt = K >> 6;  // K-tiles of 64; K % 128 == 0 for all our shapes

    floatx4 acc[2][2][4][2];
#pragma unroll
    for (int a = 0; a < 2; ++a)
#pragma unroll
        for (int bq = 0; bq < 2; ++bq)
#pragma unroll
            for (int i = 0; i < 4; ++i)
#pragma unroll
                for (int j = 0; j < 2; ++j) acc[a][bq][i][j] = (floatx4)(0.f);

    short8 areg[4][2];
    short8 breg[2][2][2];

    // prologue: tile0 fully, tile1 all but Ah1; vmcnt(6) retires exactly tile0
    STAGE_A(0, 0, 0); STAGE_B(0, 0, 0); STAGE_B(0, 1, 0); STAGE_A(0, 1, 0);
    STAGE_A(1, 0, 1); STAGE_B(1, 0, 1); STAGE_B(1, 1, 1);
    asm volatile("s_waitcnt vmcnt(6)" ::: "memory");
    __builtin_amdgcn_s_barrier();

    for (int kt = 0; kt < nkt; kt += 2) {
        WINDOW(kt, 0);
        WINDOW(kt + 1, 1);
    }

    __syncthreads();  // union transition: all LDS reads done before C staging
#pragma unroll
    for (int qm = 0; qm < 2; ++qm)
#pragma unroll
        for (int qn = 0; qn < 2; ++qn)
#pragma unroll
            for (int i = 0; i < 4; ++i)
#pragma unroll
                for (int j = 0; j < 2; ++j) {
                    const int rl = qm * 128 + wm * 64 + i * 16 + quad * 4;
                    const int cl = qn * 128 + wn * 32 + j * 16 + l16;
#pragma unroll
                    for (int rg = 0; rg < 4; ++rg)
                        sh.c[(rl + rg) * 256 + cl] = f2bf(acc[qm][qn][i][j][rg]);
                }
    __syncthreads();
#pragma unroll
    for (int sw = 0; sw < 16; ++sw) {
        const int idx = sw * 512 + t;
        const int row = idx >> 5;
        const int ch = (idx & 31) * 8;
        const int grow = bm + row;
        if (grow < M)
            *(uint4*)(C + (size_t)grow * N + bn + ch) = *(const uint4*)&sh.c[row * 256 + ch];
    }
}

#undef STAGE_A
#undef STAGE_B
#undef LOAD_A
#undef LOAD_B
#undef MFMA_Q
#undef PHASE_SYNC
#undef WINDOW

// ---------------- wave-per-dst segmented mean + root + bias (+relu/cast) ---------
// One 64-lane wave per dst node. Lane owns DIM/64 columns (16 B for DIM=512,
// 8 B for DIM=256) -> a wave pulls a full row chunk per edge. Edge descriptors
// {src|rel<<27, 1/c} are precomputed at sort time: the inner loop is pure
// gather+FMA with 8 independent loads in flight per lane (static indexing).

template <int DIM, bool L1MODE>
__global__ __launch_bounds__(64) void segsum_wave(const ushort_t* __restrict__ H,
                                                  const float* __restrict__ bias,
                                                  const int* __restrict__ off,
                                                  const int* __restrict__ cnt,
                                                  const uint2* __restrict__ edesc,
                                                  ushort_t* __restrict__ outb,
                                                  float* __restrict__ outf) {
    constexpr int VPT = DIM / 64;   // cols per lane: 8 (L1) or 4 (L2)
    constexpr int WPT = VPT / 2;    // uints per lane: 4 or 2
    const int d = blockIdx.x;
    const int t = threadIdx.x;
    const int hs = (N_REL + 1) * DIM;

    const int base = off[d * N_REL];
    const int total = off[d * N_REL + N_REL - 1] + cnt[d * N_REL + N_REL - 1] - base;

    // root + bias
    float acc[VPT];
    {
        uint_t rw[WPT];
        const ushort_t* hp = H + (size_t)d * hs + VPT * t;
        if constexpr (WPT == 4) *(uint4*)rw = *(const uint4*)hp;
        else                    *(uint2*)rw = *(const uint2*)hp;
#pragma unroll
        for (int jq = 0; jq < WPT; ++jq) {
            acc[2 * jq]     = __uint_as_float(rw[jq] << 16);
            acc[2 * jq + 1] = __uint_as_float(rw[jq] & 0xffff0000u);
        }
        const float* bp = bias + VPT * t;
#pragma unroll
        for (int jq = 0; jq < VPT; ++jq) acc[jq] += bp[jq];
    }

    const uint2* __restrict__ ed = edesc + base;
    const ushort_t* __restrict__ Hlane = H + VPT * t;

    int p = 0;
    while (p + 8 <= total) {
        uint2 dsc[8];
#pragma unroll
        for (int q = 0; q < 8; ++q) dsc[q] = ed[p + q];
        uint_t val[8][WPT];
#pragma unroll
        for (int q = 0; q < 8; ++q) {
            const uint_t pk = dsc[q].x;
            const size_t s = pk & 0x07ffffffu;
            const int r = pk >> 27;
            const ushort_t* hp = Hlane + s * hs + (r + 1) * DIM;
            if constexpr (WPT == 4) *(uint4*)val[q] = *(const uint4*)hp;
            else                    *(uint2*)val[q] = *(const uint2*)hp;
        }
#pragma unroll
        for (int q = 0; q < 8; ++q) {
            const float inv = __uint_as_float(dsc[q].y);
#pragma unroll
            for (int jq = 0; jq < WPT; ++jq) {
                acc[2 * jq]     += inv * __uint_as_float(val[q][jq] << 16);
                acc[2 * jq + 1] += inv * __uint_as_float(val[q][jq] & 0xffff0000u);
            }
        }
        p += 8;
    }
    for (; p < total; ++p) {
        const uint2 dq = ed[p];
        const uint_t pk = dq.x;
        const size_t s = pk & 0x07ffffffu;
        const int r = pk >> 27;
        const float inv = __uint_as_float(dq.y);
        uint_t vw[WPT];
        const ushort_t* hp = Hlane + s * hs + (r + 1) * DIM;
        if constexpr (WPT == 4) *(uint4*)vw = *(const uint4*)hp;
        else                    *(uint2*)vw = *(const uint2*)hp;
#pragma unroll
        for (int jq = 0; jq < WPT; ++jq) {
            acc[2 * jq]     += inv * __uint_as_float(vw[jq] << 16);
            acc[2 * jq + 1] += inv * __uint_as_float(vw[jq] & 0xffff0000u);
        }
    }

    if constexpr (L1MODE) {
        ushort_t ob[VPT];
#pragma unroll
        for (int jq = 0; jq < VPT; ++jq) ob[jq] = f2bf(fmaxf(acc[jq], 0.f));
        if constexpr (WPT == 4)
            *(uint4*)(outb + (size_t)d * DIM + VPT * t) = *(const uint4*)ob;
        else
            *(uint2*)(outb + (size_t)d * DIM + VPT * t) = *(const uint2*)ob;
    } else {
        float* op = outf + (size_t)d * DIM + VPT * t;
#pragma unroll
        for (int jq = 0; jq < WPT; ++jq)
            *(float2*)(op + 2 * jq) = make_float2(acc[2 * jq], acc[2 * jq + 1]);
    }
}

// ---------------- launcher ----------------

extern "C" void kernel_launch(void* const* d_in, const int* in_sizes, int n_in,
                              void* d_out, int out_size, void* d_ws, size_t ws_size,
                              hipStream_t stream) {
    const float* x     = (const float*)d_in[0];
    const int*   eidx  = (const int*)d_in[1];
    const int*   etype = (const int*)d_in[2];
    const float* W1    = (const float*)d_in[3];
    const float* root1 = (const float*)d_in[4];
    const float* b1    = (const float*)d_in[5];
    const float* W2    = (const float*)d_in[6];
    const float* root2 = (const float*)d_in[7];
    const float* b2    = (const float*)d_in[8];
    float* out = (float*)d_out;

    const int IN_DIM = 1280, HID_DIM = 512, OUT_DIM = 256;
    const int E = in_sizes[2];
    const int N = in_sizes[0] / IN_DIM;
    const int NK = N * N_REL;
    const int* srcs = eidx;
    const int* dsts = eidx + E;

    char* ws = (char*)d_ws;
    size_t offb = 0;
    auto alloc = [&](size_t bytes) { void* p = ws + offb; offb += (bytes + 255) & ~(size_t)255; return p; };
    int*      cnt    = (int*)alloc((size_t)NK * 4);
    int*      off    = (int*)alloc((size_t)NK * 4);
    int*      cursor = (int*)alloc((size_t)NK * 4);
    int*      bsum   = (int*)alloc(1024 * 4);
    uint2*    edesc  = (uint2*)alloc((size_t)E * 8);
    ushort_t* x_bf   = (ushort_t*)alloc((size_t)N * IN_DIM * 2);   // reused as hb_bf later
    ushort_t* rW1t   = (ushort_t*)alloc((size_t)(N_REL + 1) * IN_DIM * HID_DIM * 2);
    ushort_t* r1t    = rW1t;
    ushort_t* W1t    = rW1t + (size_t)HID_DIM * IN_DIM;
    ushort_t* rW2t   = (ushort_t*)alloc((size_t)(N_REL + 1) * HID_DIM * OUT_DIM * 2);
    ushort_t* r2t    = rW2t;
    ushort_t* W2t    = rW2t + (size_t)OUT_DIM * HID_DIM;
    ushort_t* Hb     = (ushort_t*)alloc((size_t)N * (N_REL + 1) * HID_DIM * 2);  // 184 MB
    ushort_t* hb_bf  = x_bf;  // x_bf dead after layer-1 GEMM
    (void)ws_size;

    const int nb = (NK + 255) / 256;

    // 1) sort edges by (dst, rel); build per-edge descriptors {src|rel<<27, 1/c}
    hipMemsetAsync(cnt, 0, (size_t)NK * 4, stream);
    hist_kernel<<<(E + 255) / 256, 256, 0, stream>>>(dsts, etype, cnt, E);
    scan1<<<nb, 256, 0, stream>>>(cnt, off, bsum, NK);
    scan2<<<1, 1024, 0, stream>>>(bsum, nb);
    scan3<<<nb, 256, 0, stream>>>(off, bsum, cursor, NK);
    scatter_desc<<<(E + 255) / 256, 256, 0, stream>>>(dsts, etype, srcs, cnt, cursor, edesc, E);

    // 2) casts / weight transposes (into the concatenated Bt buffers)
    {
        long n = (long)N * IN_DIM;
        cast_bf16<<<(unsigned)((n / 4 + 255) / 256), 256, 0, stream>>>(x, x_bf, n);
    }
    transpose_cast<<<dim3(HID_DIM / 32, IN_DIM / 32, 1), 256, 0, stream>>>(root1, r1t, IN_DIM, HID_DIM);
    transpose_cast<<<dim3(HID_DIM / 32, IN_DIM / 32, N_REL), 256, 0, stream>>>(W1, W1t, IN_DIM, HID_DIM);
    transpose_cast<<<dim3(OUT_DIM / 32, HID_DIM / 32, 1), 256, 0, stream>>>(root2, r2t, HID_DIM, OUT_DIM);
    transpose_cast<<<dim3(OUT_DIM / 32, HID_DIM / 32, N_REL), 256, 0, stream>>>(W2, W2t, HID_DIM, OUT_DIM);

    const int mb = (N + 255) / 256;  // 79

    // 3) layer 1: fused GEMM (root + 8 relations, N=4608) -> wave segsum+relu+cast
    {
        const int NTOT = (N_REL + 1) * HID_DIM;  // 4608
        gemm256<<<dim3(NTOT / 256, mb), 512, 0, stream>>>(x_bf, rW1t, Hb, N, IN_DIM, NTOT);
        segsum_wave<512, true><<<N, 64, 0, stream>>>(Hb, b1, off, cnt, edesc, hb_bf, nullptr);
    }

    // 4) layer 2: fused GEMM (root + 8 relations, N=2304) -> wave segsum -> out
    {
        const int NTOT = (N_REL + 1) * OUT_DIM;  // 2304
        gemm256<<<dim3(NTOT / 256, mb), 512, 0, stream>>>(hb_bf, rW2t, Hb, N, HID_DIM, NTOT);
        segsum_wave<256, false><<<N, 64, 0, stream>>>(Hb, b2, off, cnt, edesc, nullptr, out);
    }
}